// Round 1
// baseline (126.098 us; speedup 1.0000x reference)
//
#include <hip/hip_runtime.h>

#define IN_F 4096
#define OUT_F 11008
#define Q_OUT (OUT_F / 2)     // 5504
#define GROUP 128
#define BATCH 32
#define NG (IN_F / GROUP)     // 32

// main kernel decomposition
#define KB 4                  // k-blocks (gridDim.y); each covers 8 groups = 1024 k
#define KS 8                  // k-slices per block; each slice = 1 group (128 k)
#define CT 16                 // col-threads per block; each owns 4 output cols
// block = CT * 2(batch halves) * KS = 256 threads; covers 64 cols, 32 batch, 1024 k

__global__ __launch_bounds__(256)
void int4_partial_kernel(const float* __restrict__ inp,     // [32][4096]
                         const int*   __restrict__ qw,      // [4096][5504] packed bytes
                         const float* __restrict__ scales,  // [32][11008]
                         const int*   __restrict__ qz,      // [32][5504]  packed bytes
                         float*       __restrict__ partial) // [KB][32][11008]
{
    const int tid = threadIdx.x;
    const int ct  = tid & 15;          // 0..15 col-thread
    const int bh  = (tid >> 4) & 1;    // 0..1  batch half
    const int ks  = tid >> 5;          // 0..7  k-slice (one group each)
    const int cb  = blockIdx.x;        // 0..171
    const int kb  = blockIdx.y;        // 0..3

    const int pc0 = cb * 32 + ct * 2;  // packed column base (2 packed cols)
    const int n0  = pc0 * 2;           // 4 output columns n0..n0+3
    const int g   = kb * KS + ks;      // quant group index, 0..31
    const int k0  = g * GROUP;
    const int b0  = bh * 16;

    // dequant constants for the 4 owned columns (low nibble -> even col)
    const int zp0 = qz[g * Q_OUT + pc0];
    const int zp1 = qz[g * Q_OUT + pc0 + 1];
    const float4 sc = *reinterpret_cast<const float4*>(scales + (size_t)g * OUT_F + n0);
    const float zs0 = (float)(zp0 & 0xF)        * sc.x;
    const float zs1 = (float)((zp0 >> 4) & 0xF) * sc.y;
    const float zs2 = (float)(zp1 & 0xF)        * sc.z;
    const float zs3 = (float)((zp1 >> 4) & 0xF) * sc.w;

    float acc[4][16];
    #pragma unroll
    for (int c = 0; c < 4; ++c)
        #pragma unroll
        for (int b = 0; b < 16; ++b) acc[c][b] = 0.0f;

    const float* ip  = inp + (size_t)b0 * IN_F + k0;
    const int*   qwp = qw  + (size_t)k0 * Q_OUT + pc0;

    for (int kk = 0; kk < GROUP; kk += 4) {
        int2 q0 = *reinterpret_cast<const int2*>(qwp + (size_t)(kk + 0) * Q_OUT);
        int2 q1 = *reinterpret_cast<const int2*>(qwp + (size_t)(kk + 1) * Q_OUT);
        int2 q2 = *reinterpret_cast<const int2*>(qwp + (size_t)(kk + 2) * Q_OUT);
        int2 q3 = *reinterpret_cast<const int2*>(qwp + (size_t)(kk + 3) * Q_OUT);

        const int qx[4] = {q0.x, q1.x, q2.x, q3.x};
        const int qy[4] = {q0.y, q1.y, q2.y, q3.y};
        float w0[4], w1[4], w2[4], w3[4];
        #pragma unroll
        for (int j = 0; j < 4; ++j) {
            w0[j] = fmaf((float)(qx[j] & 0xF),        sc.x, -zs0);
            w1[j] = fmaf((float)((qx[j] >> 4) & 0xF), sc.y, -zs1);
            w2[j] = fmaf((float)(qy[j] & 0xF),        sc.z, -zs2);
            w3[j] = fmaf((float)((qy[j] >> 4) & 0xF), sc.w, -zs3);
        }

        #pragma unroll
        for (int b = 0; b < 16; ++b) {
            float4 iv = *reinterpret_cast<const float4*>(ip + (size_t)b * IN_F + kk);
            acc[0][b] = fmaf(iv.w, w0[3], fmaf(iv.z, w0[2], fmaf(iv.y, w0[1], fmaf(iv.x, w0[0], acc[0][b]))));
            acc[1][b] = fmaf(iv.w, w1[3], fmaf(iv.z, w1[2], fmaf(iv.y, w1[1], fmaf(iv.x, w1[0], acc[1][b]))));
            acc[2][b] = fmaf(iv.w, w2[3], fmaf(iv.z, w2[2], fmaf(iv.y, w2[1], fmaf(iv.x, w2[0], acc[2][b]))));
            acc[3][b] = fmaf(iv.w, w3[3], fmaf(iv.z, w3[2], fmaf(iv.y, w3[1], fmaf(iv.x, w3[0], acc[3][b]))));
        }
    }

    // in-block tree reduction over the 8 k-slices.
    // transposed LDS layout: lds[i*128 + slot] -> consecutive lanes hit
    // consecutive addresses (conflict-free); runs 3x total, cost negligible.
    __shared__ float red[64 * 128];   // 32 KB
    float* accf = &acc[0][0];
    for (int s = 4; s > 0; s >>= 1) {
        __syncthreads();
        if (ks >= s && ks < 2 * s) {
            const int slot = (ks - s) * 32 + bh * 16 + ct;
            #pragma unroll
            for (int i = 0; i < 64; ++i) red[i * 128 + slot] = accf[i];
        }
        __syncthreads();
        if (ks < s) {
            const int slot = ks * 32 + bh * 16 + ct;
            #pragma unroll
            for (int i = 0; i < 64; ++i) accf[i] += red[i * 128 + slot];
        }
    }

    if (ks == 0) {
        #pragma unroll
        for (int b = 0; b < 16; ++b) {
            float4 v;
            v.x = acc[0][b]; v.y = acc[1][b]; v.z = acc[2][b]; v.w = acc[3][b];
            *reinterpret_cast<float4*>(partial + ((size_t)(kb * BATCH + b0 + b)) * OUT_F + n0) = v;
        }
    }
}

__global__ __launch_bounds__(256)
void reduce_bias_kernel(const float* __restrict__ partial,  // [KB][32][11008]
                        const float* __restrict__ bias,     // [11008]
                        float*       __restrict__ out)      // [32][11008]
{
    const int i4 = (blockIdx.x * 256 + threadIdx.x) * 4;    // < 352256
    const int n  = i4 % OUT_F;                              // OUT_F % 4 == 0
    float4 s = *reinterpret_cast<const float4*>(bias + n);
    #pragma unroll
    for (int kb = 0; kb < KB; ++kb) {
        float4 p = *reinterpret_cast<const float4*>(partial + (size_t)kb * BATCH * OUT_F + i4);
        s.x += p.x; s.y += p.y; s.z += p.z; s.w += p.w;
    }
    *reinterpret_cast<float4*>(out + i4) = s;
}

extern "C" void kernel_launch(void* const* d_in, const int* in_sizes, int n_in,
                              void* d_out, int out_size, void* d_ws, size_t ws_size,
                              hipStream_t stream)
{
    const float* inp    = (const float*)d_in[0];
    const int*   qw     = (const int*)d_in[1];
    const float* scales = (const float*)d_in[2];
    const int*   qz     = (const int*)d_in[3];
    const float* bias   = (const float*)d_in[4];
    float*       out    = (float*)d_out;
    float*       partial = (float*)d_ws;   // KB*32*11008 floats = 5.63 MB

    dim3 grid(OUT_F / 64, KB);             // (172, 4)
    int4_partial_kernel<<<grid, 256, 0, stream>>>(inp, qw, scales, qz, partial);

    reduce_bias_kernel<<<(BATCH * OUT_F) / (256 * 4), 256, 0, stream>>>(partial, bias, out);
}

// Round 2
// 34.880 us; speedup vs baseline: 3.6152x; 3.6152x over previous
//
#include <hip/hip_runtime.h>
#include <cstdint>

#define IN_F 4096
#define OUT_F 11008
#define Q_OUT 5504
#define GROUP 128
#define BATCH 32

#define BN 128          // output cols per block
#define BK 64           // k per chunk
#define BROW 68         // padded LDS row stride (ints) for B tile: 64 data + 4 pad
                        // bank = (17*w + k) % 32 -> frag reads conflict-free

typedef __bf16 bf16x8 __attribute__((ext_vector_type(8)));
typedef float  f32x4  __attribute__((ext_vector_type(4)));

// ---------------------------------------------------------------------------
// Prepass: X f32 [32][4096] -> bf16 in MFMA A-fragment order.
// Global layout: for k-step S (32 k), m-frag f (16 rows), lane (64):
//   element (m = 16*f + (lane&15), k = 32*S + 8*(lane>>4) + j), j=0..7
//   stored at 16B slot index (S*2 + f)*64 + lane.
// ---------------------------------------------------------------------------
__global__ __launch_bounds__(256)
void xprep_kernel(const float* __restrict__ x, bf16x8* __restrict__ xf)
{
    const int t    = blockIdx.x * 256 + threadIdx.x;   // 0..16383
    const int lane = t & 63;
    const int f    = (t >> 6) & 1;
    const int S    = t >> 7;                           // 0..127
    const int m    = f * 16 + (lane & 15);
    const int k0   = S * 32 + (lane >> 4) * 8;
    const float4* xr = reinterpret_cast<const float4*>(x + (size_t)m * IN_F + k0);
    float4 a = xr[0], b = xr[1];
    bf16x8 v;
    v[0] = (__bf16)a.x; v[1] = (__bf16)a.y; v[2] = (__bf16)a.z; v[3] = (__bf16)a.w;
    v[4] = (__bf16)b.x; v[5] = (__bf16)b.y; v[6] = (__bf16)b.z; v[7] = (__bf16)b.w;
    xf[t] = v;
}

// ---------------------------------------------------------------------------
// Main GEMM: per block M=32, N=128, K = GPB*128. 4 waves, each owns 32 cols.
// B staged raw (packed int32) global->reg->LDS transposed [w][k] (pad 68);
// dequant fused into B-fragment build; A from frag-ordered bf16 (lane-linear).
// ---------------------------------------------------------------------------
template<int GPB>
__global__ __launch_bounds__(256)
void int4_gemm_kernel(const uint4* __restrict__ xf,
                      const int*   __restrict__ qw,
                      const float* __restrict__ scales,
                      const int*   __restrict__ qz,
                      float*       __restrict__ partial)
{
    constexpr int NCH = GPB * 2;          // 64-k chunks per block
    const int tid  = threadIdx.x;
    const int lane = tid & 63;
    const int wid  = tid >> 6;            // 0..3
    const int nb   = blockIdx.x;          // 0..85
    const int kb   = blockIdx.y;
    const int g0   = kb * GPB;            // first quant group of this block
    const int k0b  = g0 * GROUP;          // block k base

    __shared__ uint4 a_lds[2][256];           // 2 x 4 KB  (frag-ordered A chunk)
    __shared__ int   b_lds[2][64 * BROW];     // 2 x 17.4 KB (transposed raw B)

    const int cl = lane & 15;             // col within 16-col frag
    const int kg = lane >> 4;             // k-group 0..3
    const int sh = (cl & 1) * 4;          // nibble shift (even col -> low)

    // preload scale and zero*scale for all groups this block touches
    float scv[2][GPB], zsv[2][GPB];
    #pragma unroll
    for (int nf = 0; nf < 2; ++nf) {
        const int n = nb * BN + wid * 32 + nf * 16 + cl;
        #pragma unroll
        for (int g = 0; g < GPB; ++g) {
            const float s = scales[(size_t)(g0 + g) * OUT_F + n];
            const int   z = (qz[(size_t)(g0 + g) * Q_OUT + (n >> 1)] >> sh) & 15;
            scv[nf][g] = s;
            zsv[nf][g] = s * (float)z;
        }
    }

    uint4 areg;
    int4  breg[4];
    const int bw4 = (tid & 15) * 4;       // local w 0..60 (4 int32 each)
    const int bkl = tid >> 4;             // k row 0..15 (+16 per round)

    f32x4 acc[2][2] = {};

    auto LOADG = [&](int c) {
        areg = xf[(size_t)(k0b / 32 + c * 2) * 128 + tid];
        const int krow = k0b + c * BK + bkl;
        #pragma unroll
        for (int r = 0; r < 4; ++r)
            breg[r] = *reinterpret_cast<const int4*>(
                qw + (size_t)(krow + 16 * r) * Q_OUT + nb * 64 + bw4);
    };
    auto WLDS = [&](int buf) {
        a_lds[buf][tid] = areg;
        #pragma unroll
        for (int r = 0; r < 4; ++r) {
            const int k = bkl + 16 * r;
            b_lds[buf][(bw4 + 0) * BROW + k] = breg[r].x;
            b_lds[buf][(bw4 + 1) * BROW + k] = breg[r].y;
            b_lds[buf][(bw4 + 2) * BROW + k] = breg[r].z;
            b_lds[buf][(bw4 + 3) * BROW + k] = breg[r].w;
        }
    };

    LOADG(0);
    WLDS(0);
    __syncthreads();

    #pragma unroll                       // full unroll: keeps scv/zsv in regs
    for (int c = 0; c < NCH; ++c) {
        const int cur = c & 1;
        if (c + 1 < NCH) LOADG(c + 1);

        const int gl = c >> 1;           // group-local index (compile-time)
        #pragma unroll
        for (int s = 0; s < 2; ++s) {
            bf16x8 af0 = __builtin_bit_cast(bf16x8, a_lds[cur][(s * 2 + 0) * 64 + lane]);
            bf16x8 af1 = __builtin_bit_cast(bf16x8, a_lds[cur][(s * 2 + 1) * 64 + lane]);
            #pragma unroll
            for (int nf = 0; nf < 2; ++nf) {
                const int wloc = wid * 16 + nf * 8 + (cl >> 1);
                const int base = wloc * BROW + s * 32 + kg * 8;
                int4 q0 = *reinterpret_cast<const int4*>(&b_lds[cur][base]);
                int4 q1 = *reinterpret_cast<const int4*>(&b_lds[cur][base + 4]);
                const float ss = scv[nf][gl], zz = zsv[nf][gl];
                bf16x8 bfr;
                bfr[0] = (__bf16)fmaf((float)((q0.x >> sh) & 15), ss, -zz);
                bfr[1] = (__bf16)fmaf((float)((q0.y >> sh) & 15), ss, -zz);
                bfr[2] = (__bf16)fmaf((float)((q0.z >> sh) & 15), ss, -zz);
                bfr[3] = (__bf16)fmaf((float)((q0.w >> sh) & 15), ss, -zz);
                bfr[4] = (__bf16)fmaf((float)((q1.x >> sh) & 15), ss, -zz);
                bfr[5] = (__bf16)fmaf((float)((q1.y >> sh) & 15), ss, -zz);
                bfr[6] = (__bf16)fmaf((float)((q1.z >> sh) & 15), ss, -zz);
                bfr[7] = (__bf16)fmaf((float)((q1.w >> sh) & 15), ss, -zz);
                acc[0][nf] = __builtin_amdgcn_mfma_f32_16x16x32_bf16(af0, bfr, acc[0][nf], 0, 0, 0);
                acc[1][nf] = __builtin_amdgcn_mfma_f32_16x16x32_bf16(af1, bfr, acc[1][nf], 0, 0, 0);
            }
        }
        if (c + 1 < NCH) WLDS(cur ^ 1);
        __syncthreads();
    }

    // epilogue: C/D layout col = lane&15, row = (lane>>4)*4 + reg  [m89]
    #pragma unroll
    for (int f = 0; f < 2; ++f)
        #pragma unroll
        for (int nf = 0; nf < 2; ++nf) {
            const int n = nb * BN + wid * 32 + nf * 16 + cl;
            const int m = f * 16 + kg * 4;
            float* pp = partial + ((size_t)(kb * BATCH + m)) * OUT_F + n;
            pp[0]                 = acc[f][nf][0];
            pp[(size_t)OUT_F]     = acc[f][nf][1];
            pp[(size_t)OUT_F * 2] = acc[f][nf][2];
            pp[(size_t)OUT_F * 3] = acc[f][nf][3];
        }
}

__global__ __launch_bounds__(256)
void reduce_bias_kernel(const float* __restrict__ partial,
                        const float* __restrict__ bias,
                        float* __restrict__ out, int kbn)
{
    const int i4 = (blockIdx.x * 256 + threadIdx.x) * 4;   // < 352256
    const int n  = i4 % OUT_F;
    float4 s = *reinterpret_cast<const float4*>(bias + n);
    for (int kb = 0; kb < kbn; ++kb) {
        float4 p = *reinterpret_cast<const float4*>(partial + (size_t)kb * BATCH * OUT_F + i4);
        s.x += p.x; s.y += p.y; s.z += p.z; s.w += p.w;
    }
    *reinterpret_cast<float4*>(out + i4) = s;
}

extern "C" void kernel_launch(void* const* d_in, const int* in_sizes, int n_in,
                              void* d_out, int out_size, void* d_ws, size_t ws_size,
                              hipStream_t stream)
{
    const float* inp    = (const float*)d_in[0];
    const int*   qw     = (const int*)d_in[1];
    const float* scales = (const float*)d_in[2];
    const int*   qz     = (const int*)d_in[3];
    const float* bias   = (const float*)d_in[4];
    float*       out    = (float*)d_out;

    const size_t XFB = (size_t)BATCH * IN_F * 2;            // 256 KB bf16 X (frag order)
    const size_t P_PER_KB = (size_t)BATCH * OUT_F * 4;      // 1.41 MB per k-split

    bf16x8* xf      = (bf16x8*)d_ws;
    float*  partial = (float*)((char*)d_ws + XFB);

    int KBv;
    if      (ws_size >= XFB + 8 * P_PER_KB) KBv = 8;
    else if (ws_size >= XFB + 4 * P_PER_KB) KBv = 4;
    else                                    KBv = 2;

    xprep_kernel<<<64, 256, 0, stream>>>(inp, xf);

    if (KBv == 8)
        int4_gemm_kernel<4><<<dim3(OUT_F / BN, 8), 256, 0, stream>>>(
            (const uint4*)xf, qw, scales, qz, partial);
    else if (KBv == 4)
        int4_gemm_kernel<8><<<dim3(OUT_F / BN, 4), 256, 0, stream>>>(
            (const uint4*)xf, qw, scales, qz, partial);
    else
        int4_gemm_kernel<16><<<dim3(OUT_F / BN, 2), 256, 0, stream>>>(
            (const uint4*)xf, qw, scales, qz, partial);

    reduce_bias_kernel<<<(BATCH * OUT_F) / 1024, 256, 0, stream>>>(partial, bias, out, KBv);
}

// Round 3
// 31.213 us; speedup vs baseline: 4.0399x; 1.1175x over previous
//
#include <hip/hip_runtime.h>
#include <hip/hip_fp16.h>
#include <cstdint>

#define IN_F 4096
#define OUT_F 11008
#define Q_OUT 5504
#define GROUP 128
#define BATCH 32

#define KBS 8          // k-splits (gridDim.y)
#define GPB 4          // quant groups per block (32/KBS)
#define NCH 8          // 64-k chunks per block
#define BN 64          // output cols per block
#define BROWS 66       // LDS ints per w-row: 64 data + 2 pad -> bank=(2w+k)%32, 2-way (free)

typedef _Float16 f16x8 __attribute__((ext_vector_type(8)));
typedef float    f32x4 __attribute__((ext_vector_type(4)));

// ---------------------------------------------------------------------------
// Prepass: X f32 [32][4096] -> f16 in MFMA A-fragment order.
// slot(S,f,lane) = (S*2+f)*64 + lane holds (m = 16f + (lane&15),
// k = 32S + 8*(lane>>4) + j), j=0..7.
// ---------------------------------------------------------------------------
__global__ __launch_bounds__(256)
void xprep_kernel(const float* __restrict__ x, uint4* __restrict__ xf)
{
    const int t    = blockIdx.x * 256 + threadIdx.x;   // 0..16383
    const int lane = t & 63;
    const int f    = (t >> 6) & 1;
    const int S    = t >> 7;
    const int m    = f * 16 + (lane & 15);
    const int k0   = S * 32 + (lane >> 4) * 8;
    const float4* xr = reinterpret_cast<const float4*>(x + (size_t)m * IN_F + k0);
    float4 a = xr[0], b = xr[1];
    union { _Float16 h[8]; uint4 u; } v;
    v.h[0] = (_Float16)a.x; v.h[1] = (_Float16)a.y;
    v.h[2] = (_Float16)a.z; v.h[3] = (_Float16)a.w;
    v.h[4] = (_Float16)b.x; v.h[5] = (_Float16)b.y;
    v.h[6] = (_Float16)b.z; v.h[7] = (_Float16)b.w;
    xf[t] = v.u;
}

// ---------------------------------------------------------------------------
// Main GEMM: per block M=32, N=64, K=512. 4 waves, each owns 16 cols.
// A: global->register fragments (frag-ordered f16 file, L2-hot).
// B: raw int32 words staged global->reg->LDS transposed [w][k] (stride 66),
//    dequant via f16 magic numbers fused into fragment build.
// ---------------------------------------------------------------------------
__global__ __launch_bounds__(256)
void int4_gemm_kernel(const uint4* __restrict__ xf,
                      const int*   __restrict__ qw,
                      const float* __restrict__ scales,
                      const int*   __restrict__ qz,
                      float*       __restrict__ partial)
{
    const int tid  = threadIdx.x;
    const int lane = tid & 63;
    const int wid  = tid >> 6;            // 0..3
    const int nb   = blockIdx.x;          // 0..171
    const int kb   = blockIdx.y;          // 0..7
    const int g0   = kb * GPB;
    const int k0b  = g0 * GROUP;          // block k base

    __shared__ int b_lds[2][32 * BROWS];  // 2 x 8.25 KB

    const int cl  = lane & 15;            // col within 16-col frag
    const int kg  = lane >> 4;            // k-group 0..3
    const int w   = wid * 8 + (cl >> 1);  // packed-word column 0..31
    const int shn = (cl & 1) * 4;         // nibble shift (even col -> low)

    // per-group dequant constants: packed f16 magic zero and scale
    const int n = nb * BN + wid * 16 + cl;
    uint    zmu[GPB];
    __half2 spk[GPB];
    #pragma unroll
    for (int g = 0; g < GPB; ++g) {
        const float s = scales[(size_t)(g0 + g) * OUT_F + n];
        const int   z = (qz[(size_t)(g0 + g) * Q_OUT + (n >> 1)] >> shn) & 15;
        spk[g] = __float2half2_rn(s);
        zmu[g] = 0x64006400u + (uint)z * 0x00010001u;   // packed f16 (1024+z, 1024+z)
    }

    // B staging geometry: thread loads 2 x uint4 (rows bk, bk+32; 4 words at 4*a8)
    const int a8 = tid & 7;
    const int bk = tid >> 3;              // 0..31

    f32x4 acc[2] = {};
    uint4 A[2][4];                        // [buf][s*2+f] A fragments
    uint4 b0r, b1r;

    auto LOADA = [&](int c, int buf) {
        const size_t base = (size_t)(k0b / 32 + c * 2) * 128;   // uint4 slots
        A[buf][0] = xf[base +   0 + lane];
        A[buf][1] = xf[base +  64 + lane];
        A[buf][2] = xf[base + 128 + lane];
        A[buf][3] = xf[base + 192 + lane];
    };
    auto LOADB = [&](int c) {
        const int kr = k0b + c * 64;
        b0r = *reinterpret_cast<const uint4*>(qw + (size_t)(kr + bk)      * Q_OUT + nb * 32 + a8 * 4);
        b1r = *reinterpret_cast<const uint4*>(qw + (size_t)(kr + bk + 32) * Q_OUT + nb * 32 + a8 * 4);
    };
    auto WLDS = [&](int buf) {
        int* p = b_lds[buf];
        p[(4 * a8 + 0) * BROWS + bk] = b0r.x;
        p[(4 * a8 + 1) * BROWS + bk] = b0r.y;
        p[(4 * a8 + 2) * BROWS + bk] = b0r.z;
        p[(4 * a8 + 3) * BROWS + bk] = b0r.w;
        p[(4 * a8 + 0) * BROWS + bk + 32] = b1r.x;
        p[(4 * a8 + 1) * BROWS + bk + 32] = b1r.y;
        p[(4 * a8 + 2) * BROWS + bk + 32] = b1r.z;
        p[(4 * a8 + 3) * BROWS + bk + 32] = b1r.w;
    };

    LOADA(0, 0);
    LOADB(0);
    WLDS(0);
    __syncthreads();

    #pragma unroll
    for (int c = 0; c < NCH; ++c) {
        const int cur = c & 1;
        if (c + 1 < NCH) { LOADA(c + 1, cur ^ 1); LOADB(c + 1); }

        const int     gl  = c >> 1;                 // compile-time group index
        const __half2 zmh = __builtin_bit_cast(__half2, zmu[gl]);
        const __half2 sg  = spk[gl];

        #pragma unroll
        for (int s = 0; s < 2; ++s) {
            const int* bp = &b_lds[cur][w * BROWS + s * 32 + kg * 8];
            int2 q0 = *reinterpret_cast<const int2*>(bp + 0);
            int2 q1 = *reinterpret_cast<const int2*>(bp + 2);
            int2 q2 = *reinterpret_cast<const int2*>(bp + 4);
            int2 q3 = *reinterpret_cast<const int2*>(bp + 6);

            union { uint u[4]; f16x8 v; } bf;
            const int2 qq[4] = {q0, q1, q2, q3};
            #pragma unroll
            for (int t = 0; t < 4; ++t) {
                // pack byte(k), byte(k+1) -> halves; magic-bias to f16 1024+q
                uint pr = __builtin_amdgcn_perm((uint)qq[t].y, (uint)qq[t].x, 0x0C040C00u);
                pr >>= shn;
                uint qk = (pr & 0x000F000Fu) | 0x64006400u;
                __half2 wv = __hmul2(__hsub2(__builtin_bit_cast(__half2, qk), zmh), sg);
                bf.u[t] = __builtin_bit_cast(uint, wv);
            }
            f16x8 af0 = __builtin_bit_cast(f16x8, A[cur][s * 2 + 0]);
            f16x8 af1 = __builtin_bit_cast(f16x8, A[cur][s * 2 + 1]);
            acc[0] = __builtin_amdgcn_mfma_f32_16x16x32_f16(af0, bf.v, acc[0], 0, 0, 0);
            acc[1] = __builtin_amdgcn_mfma_f32_16x16x32_f16(af1, bf.v, acc[1], 0, 0, 0);
        }

        if (c + 1 < NCH) WLDS(cur ^ 1);
        __syncthreads();
    }

    // epilogue: C/D layout col = lane&15, row = (lane>>4)*4 + reg  [m89]
    #pragma unroll
    for (int f = 0; f < 2; ++f) {
        const int m = f * 16 + kg * 4;
        float* pp = partial + ((size_t)(kb * BATCH + m)) * OUT_F + n;
        pp[0]                 = acc[f][0];
        pp[(size_t)OUT_F]     = acc[f][1];
        pp[(size_t)OUT_F * 2] = acc[f][2];
        pp[(size_t)OUT_F * 3] = acc[f][3];
    }
}

__global__ __launch_bounds__(256)
void reduce_bias_kernel(const float* __restrict__ partial,
                        const float* __restrict__ bias,
                        float* __restrict__ out)
{
    const int i4 = (blockIdx.x * 256 + threadIdx.x) * 4;   // < 352256
    const int n  = i4 % OUT_F;
    float4 s = *reinterpret_cast<const float4*>(bias + n);
    #pragma unroll
    for (int kb = 0; kb < KBS; ++kb) {
        float4 p = *reinterpret_cast<const float4*>(partial + (size_t)kb * BATCH * OUT_F + i4);
        s.x += p.x; s.y += p.y; s.z += p.z; s.w += p.w;
    }
    *reinterpret_cast<float4*>(out + i4) = s;
}

extern "C" void kernel_launch(void* const* d_in, const int* in_sizes, int n_in,
                              void* d_out, int out_size, void* d_ws, size_t ws_size,
                              hipStream_t stream)
{
    const float* inp    = (const float*)d_in[0];
    const int*   qw     = (const int*)d_in[1];
    const float* scales = (const float*)d_in[2];
    const int*   qz     = (const int*)d_in[3];
    const float* bias   = (const float*)d_in[4];
    float*       out    = (float*)d_out;

    const size_t XFB = (size_t)BATCH * IN_F * 2;            // 256 KB f16 X (frag order)
    uint4* xf      = (uint4*)d_ws;
    float* partial = (float*)((char*)d_ws + XFB);           // KBS * 1.41 MB

    xprep_kernel<<<64, 256, 0, stream>>>(inp, xf);

    int4_gemm_kernel<<<dim3(OUT_F / BN, KBS), 256, 0, stream>>>(
        xf, qw, scales, qz, partial);

    reduce_bias_kernel<<<(BATCH * OUT_F) / 1024, 256, 0, stream>>>(partial, bias, out);
}